// Round 15
// baseline (76.686 us; speedup 1.0000x reference)
//
#include <hip/hip_runtime.h>
#include <hip/hip_bf16.h>
#include <math.h>

#define NQ    16384
#define BS    2
#define HID   256
#define NCAM  6
#define NPTS  4
#define CF    256
#define HF    28
#define WF    50
#define HWF   (HF*WF)
#define NIMG  (BS*NCAM)
#define EPSV  1e-5f

typedef __attribute__((ext_vector_type(8))) short short8v;
typedef __attribute__((ext_vector_type(4))) float float4v;

__device__ __forceinline__ unsigned short f2bf(float f) {
    unsigned u = __float_as_uint(f);
    u += 0x7fffu + ((u >> 16) & 1u);
    return (unsigned short)(u >> 16);
}
__device__ __forceinline__ unsigned pkbf(float lo, float hi) {
    __hip_bfloat162 h = __float22bfloat162_rn(float2{lo, hi});
    return *reinterpret_cast<unsigned*>(&h);
}
__device__ __forceinline__ float bfLO(unsigned u) { return __uint_as_float(u << 16); }
__device__ __forceinline__ float bfHI(unsigned u) { return __uint_as_float(u & 0xffff0000u); }

// ---------------- K1: pre-pass: featsT + WoT + aw + geometry (round-12 proven) ----------------
__global__ __launch_bounds__(256) void prep_aw(
    const float* __restrict__ feats, const float* __restrict__ Wo,
    const float* __restrict__ Wa,    const float* __restrict__ query,
    const float* __restrict__ query_pos, const float* __restrict__ ba,
    const float* __restrict__ rho,   const float* __restrict__ phi,
    const float* __restrict__ zz,    const float* __restrict__ l2i,
    const float* __restrict__ intervals, const float* __restrict__ pc_range,
    const float* __restrict__ img_size,
    unsigned short* __restrict__ featsT, unsigned short* __restrict__ WoT,
    float* __restrict__ ws, float* __restrict__ gxy, float* __restrict__ out)
{
    __shared__ __align__(16) char smem[32 * 264 * 2];   // 16896 B

    const int tx = threadIdx.x & 31;
    const int ty = threadIdx.x >> 5;
    if (blockIdx.x < 528) {
        float (*tile)[33] = reinterpret_cast<float(*)[33]>(smem);
        const int img = blockIdx.x / 44;
        const int hw0 = (blockIdx.x % 44) * 32;
        for (int ct = 0; ct < 8; ++ct) {
            const int c0 = ct * 32;
            #pragma unroll
            for (int i = 0; i < 4; ++i) {
                const int c  = c0 + ty + 8 * i;
                const int hw = hw0 + tx;
                tile[ty + 8 * i][tx] = (hw < HWF) ? feats[((size_t)img * CF + c) * HWF + hw] : 0.f;
            }
            __syncthreads();
            #pragma unroll
            for (int i = 0; i < 4; ++i) {
                const int hw = hw0 + ty + 8 * i;
                if (hw < HWF)
                    featsT[((size_t)img * HWF + hw) * CF + c0 + tx] = f2bf(tile[tx][ty + 8 * i]);
            }
            __syncthreads();
        }
    } else if (blockIdx.x < 592) {
        float (*tile)[33] = reinterpret_cast<float(*)[33]>(smem);
        const int bid = blockIdx.x - 528;
        const int kt = bid >> 3, nt = bid & 7;
        #pragma unroll
        for (int i = 0; i < 4; ++i)
            tile[ty + 8 * i][tx] = Wo[(size_t)(kt * 32 + ty + 8 * i) * HID + nt * 32 + tx];
        __syncthreads();
        #pragma unroll
        for (int i = 0; i < 4; ++i)
            WoT[(size_t)(nt * 32 + ty + 8 * i) * HID + kt * 32 + tx] = f2bf(tile[tx][ty + 8 * i]);
    } else if (blockIdx.x < 1104) {
        unsigned short (*waL)[264] = reinterpret_cast<unsigned short(*)[264]>(smem);
        #pragma unroll
        for (int s = 0; s < 32; ++s)
            waL[s][threadIdx.x] = (s < 24) ? f2bf(Wa[threadIdx.x * 24 + s]) : (unsigned short)0;
        __syncthreads();

        const int bid  = blockIdx.x - 592;
        const int wave = threadIdx.x >> 6;
        const int lane = threadIdx.x & 63;
        const int arow = lane & 15;
        const int g4   = lane >> 4;
        const int g0   = (bid * 4 + wave) * 16;
        const int ga   = g0 + arow;
        const int bb   = ga >> 14;
        const int qq   = ga & (NQ - 1);
        const float* qp1 = query     + ((size_t)qq * BS + bb) * HID;
        const float* qp2 = query_pos + ((size_t)qq * BS + bb) * HID;

        float4v aw0 = {0.f,0.f,0.f,0.f}, aw1 = {0.f,0.f,0.f,0.f};
        #pragma unroll
        for (int kk = 0; kk < 8; ++kk) {
            const int k0 = kk * 32 + g4 * 8;
            const float4 a0 = *reinterpret_cast<const float4*>(qp1 + k0);
            const float4 a1 = *reinterpret_cast<const float4*>(qp1 + k0 + 4);
            const float4 p0 = *reinterpret_cast<const float4*>(qp2 + k0);
            const float4 p1 = *reinterpret_cast<const float4*>(qp2 + k0 + 4);
            union { uint4 u; short8v s; } af;
            af.u.x = pkbf(a0.x + p0.x, a0.y + p0.y);
            af.u.y = pkbf(a0.z + p0.z, a0.w + p0.w);
            af.u.z = pkbf(a1.x + p1.x, a1.y + p1.y);
            af.u.w = pkbf(a1.z + p1.z, a1.w + p1.w);
            const short8v b0 = *reinterpret_cast<const short8v*>(&waL[arow][k0]);
            const short8v b1 = *reinterpret_cast<const short8v*>(&waL[16 + arow][k0]);
            aw0 = __builtin_amdgcn_mfma_f32_16x16x32_bf16(af.s, b0, aw0, 0, 0, 0);
            aw1 = __builtin_amdgcn_mfma_f32_16x16x32_bf16(af.s, b1, aw1, 0, 0, 0);
        }
        const float ba0 = ba[arow];
        const float ba1 = (arow < 8) ? ba[16 + arow] : 0.f;
        #pragma unroll
        for (int i = 0; i < 4; ++i) {
            float s0 = 1.0f / (1.0f + __expf(-(aw0[i] + ba0)));
            float s1 = (arow < 8) ? 1.0f / (1.0f + __expf(-(aw1[i] + ba1))) : 0.f;
            s0 += __shfl_xor(s0, 1);  s0 += __shfl_xor(s0, 2);
            s1 += __shfl_xor(s1, 1);  s1 += __shfl_xor(s1, 2);
            if ((arow & 3) == 0) {
                const int gq = g0 + g4 * 4 + i;
                ws[(size_t)gq * 8 + (arow >> 2)] = s0;
                if (arow < 8)
                    ws[(size_t)gq * 8 + 4 + (arow >> 2)] = s1;
            }
        }
    } else {
        const int pair = (blockIdx.x - 1104) * 256 + threadIdx.x;   // 0..196607
        const int gq   = pair / 6;
        const int cam  = pair - gq * 6;
        const int bb   = gq >> 14;
        const int qn   = gq & (NQ - 1);
        const float pc0 = pc_range[0], pc1 = pc_range[1];
        const float pc2 = pc_range[2], pc3 = pc_range[3];
        const float rr = rho[qn] * pc0 + intervals[0] * 0.5f;
        const float pp = phi[qn] * pc1 - 3.14159265358979323846f + intervals[1] * 0.5f;
        const float xx = rr * cosf(pp);
        const float yy = rr * sinf(pp);
        const float z  = zz[bb * NQ + qn] * (pc3 - pc2) + pc2;
        const float* M = l2i + (bb * NCAM + cam) * 16;
        const float cx = M[0]*xx + M[1]*yy + M[2]*z  + M[3];
        const float cy = M[4]*xx + M[5]*yy + M[6]*z  + M[7];
        const float cz = M[8]*xx + M[9]*yy + M[10]*z + M[11];
        const float d  = fmaxf(cz, EPSV);
        const float gx = (cx / d / img_size[0] - 0.5f) * 2.0f;
        const float gy = (cy / d / img_size[1] - 0.5f) * 2.0f;
        const bool  mk = (cz > EPSV) && (gx > -1.0f) && (gx < 1.0f)
                                     && (gy > -1.0f) && (gy < 1.0f);
        gxy[(size_t)gq * 12 + cam * 2]     = mk ? gx : -3.0f;
        gxy[(size_t)gq * 12 + cam * 2 + 1] = mk ? gy : 0.0f;
        out[(size_t)NQ * BS * HID + pair]  = mk ? 1.0f : 0.0f;
    }
}

// ---------------- K2: main kernel — branch-free grouped gather + asm Phase B ----------------
__global__ __launch_bounds__(512, 4) void ca_main15(
    const float* __restrict__ query, const unsigned short* __restrict__ featsT,
    const float* __restrict__ ws,    const float* __restrict__ gxy,
    const unsigned short* __restrict__ WoT, const float* __restrict__ bo,
    float* __restrict__ out)
{
    __shared__ char fab[16 * 512];   // bf16 [16][256] fa, XOR-swizzled

    const int tid  = threadIdx.x;
    const int wave = tid >> 6;
    const int lane = tid & 63;
    const int l32  = lane & 31;
    const int r    = wave * 2 + (lane >> 5);

    // XCD-aware block->query mapping: XCDs 0-3 serve batch 0, XCDs 4-7 batch 1
    const int bid  = blockIdx.x;
    const int xg   = (bid & 7) >> 2;
    const int idx  = (bid & 3) + ((bid >> 3) << 2);
    const int base = (xg << 14) + idx * 16;
    const int b    = xg;
    const int g    = base + r;

    // early independent coalesced loads (whole front-end state)
    const float wsn = ws[(size_t)g * 8 + (l32 & 7)];
    const float gv  = (l32 < 12) ? gxy[(size_t)g * 12 + l32] : 0.f;

    float gxs[NCAM], gys[NCAM], wsv[NCAM];
    #pragma unroll
    for (int n = 0; n < NCAM; ++n) {
        gxs[n] = __shfl(gv, (lane & 32) + 2 * n);
        gys[n] = __shfl(gv, (lane & 32) + 2 * n + 1);
        wsv[n] = (gxs[n] > -2.0f) ? __shfl(wsn, (lane & 32) + n) : 0.f;
    }

    // ---- branch-free gather: 2 groups of 3 cams, 12 loads in flight per group ----
    float acc[8] = {0.f,0.f,0.f,0.f,0.f,0.f,0.f,0.f};
    #pragma unroll
    for (int grp = 0; grp < 2; ++grp) {
        uint4 u[12];
        float w[12];
        #pragma unroll
        for (int ci = 0; ci < 3; ++ci) {
            const int n = grp * 3 + ci;
            const float ixf = ((gxs[n] + 1.0f) * WF - 1.0f) * 0.5f;
            const float iyf = ((gys[n] + 1.0f) * HF - 1.0f) * 0.5f;
            const float x0f = floorf(ixf), y0f = floorf(iyf);
            const float fx = ixf - x0f, fy = iyf - y0f;
            const int x0 = (int)x0f, y0 = (int)y0f;
            const int   xs[4] = {x0, x0 + 1, x0,     x0 + 1};
            const int   ys[4] = {y0, y0,     y0 + 1, y0 + 1};
            const float wc[4] = {(1.f-fx)*(1.f-fy), fx*(1.f-fy),
                                 (1.f-fx)*fy,       fx*fy};
            const unsigned short* fb = featsT + (size_t)(b * NCAM + n) * HWF * CF + 8 * l32;
            #pragma unroll
            for (int c4 = 0; c4 < 4; ++c4) {
                const bool v = (xs[c4] >= 0) && (xs[c4] < WF) &&
                               (ys[c4] >= 0) && (ys[c4] < HF);
                const int xc = min(max(xs[c4], 0), WF - 1);
                const int yc = min(max(ys[c4], 0), HF - 1);
                const unsigned short* ap = fb + (size_t)(yc * WF + xc) * CF;
                asm volatile("global_load_dwordx4 %0, %1, off"
                             : "=v"(u[ci * 4 + c4]) : "v"(ap));
                w[ci * 4 + c4] = wsv[n] * (v ? wc[c4] : 0.0f);
            }
        }
        asm volatile("s_waitcnt vmcnt(0)" ::: "memory");
        __builtin_amdgcn_sched_barrier(0);
        #pragma unroll
        for (int i = 0; i < 12; ++i) {
            acc[0] += w[i] * bfLO(u[i].x); acc[1] += w[i] * bfHI(u[i].x);
            acc[2] += w[i] * bfLO(u[i].y); acc[3] += w[i] * bfHI(u[i].y);
            acc[4] += w[i] * bfLO(u[i].z); acc[5] += w[i] * bfHI(u[i].z);
            acc[6] += w[i] * bfLO(u[i].w); acc[7] += w[i] * bfHI(u[i].w);
        }
    }

    // ---- fa row -> bf16 swizzled LDS (packed cvt); single barrier ----
    {
        uint4 u;
        u.x = pkbf(acc[0], acc[1]);
        u.y = pkbf(acc[2], acc[3]);
        u.z = pkbf(acc[4], acc[5]);
        u.w = pkbf(acc[6], acc[7]);
        *reinterpret_cast<uint4*>(fab + ((unsigned)(r * 512 + 16 * l32) ^ ((unsigned)(r & 7) << 4))) = u;
    }
    __syncthreads();

    // ---- Phase B: O[16][256] = fa @ Wo; asm-forced B prefetch, one wait per tile ----
    const int colw = lane & 15;
    const int g4   = lane >> 4;
    float4v dacc[2];
    #pragma unroll
    for (int t = 0; t < 2; ++t) {
        const int col = wave * 16 + t * 128 + colw;
        const unsigned short* bp = WoT + (size_t)col * HID + g4 * 8;
        uint4 bw[8];
        #pragma unroll
        for (int i = 0; i < 8; ++i)
            asm volatile("global_load_dwordx4 %0, %1, off"
                         : "=v"(bw[i]) : "v"(bp + (size_t)i * 32));
        short8v af[8];
        #pragma unroll
        for (int kk = 0; kk < 8; ++kk)
            af[kk] = *reinterpret_cast<const short8v*>(
                fab + ((unsigned)(colw * 512 + (kk * 32 + g4 * 8) * 2) ^ ((unsigned)(colw & 7) << 4)));
        asm volatile("s_waitcnt vmcnt(0)" ::: "memory");
        __builtin_amdgcn_sched_barrier(0);
        float4v d = {0.f,0.f,0.f,0.f};
        #pragma unroll
        for (int kk = 0; kk < 8; ++kk) {
            union { uint4 u; short8v s; } bu; bu.u = bw[kk];
            d = __builtin_amdgcn_mfma_f32_16x16x32_bf16(af[kk], bu.s, d, 0, 0, 0);
        }
        dacc[t] = d;
    }
    #pragma unroll
    for (int t = 0; t < 2; ++t) {
        const int col = wave * 16 + t * 128 + colw;
        const float boc = bo[col];
        #pragma unroll
        for (int rg = 0; rg < 4; ++rg) {
            const int row = g4 * 4 + rg;
            const int gq = base + row;
            const int bq = gq >> 14, qq = gq & (NQ - 1);
            const size_t addr = ((size_t)qq * BS + bq) * HID + col;
            out[addr] = dacc[t][rg] + boc + query[addr];
        }
    }
}

// ---------------- fallback prep (with WaT, for ca_fused3 path) ----------------
__global__ __launch_bounds__(256) void prep_all(
    const float* __restrict__ feats, const float* __restrict__ Wo,
    const float* __restrict__ Wa, unsigned short* __restrict__ featsT,
    unsigned short* __restrict__ WoT, unsigned short* __restrict__ WaT)
{
    __shared__ float tile[32][33];
    const int tx = threadIdx.x & 31;
    const int ty = threadIdx.x >> 5;
    if (blockIdx.x < 528) {
        const int img = blockIdx.x / 44;
        const int hw0 = (blockIdx.x % 44) * 32;
        for (int ct = 0; ct < 8; ++ct) {
            const int c0 = ct * 32;
            #pragma unroll
            for (int i = 0; i < 4; ++i) {
                const int c  = c0 + ty + 8 * i;
                const int hw = hw0 + tx;
                tile[ty + 8 * i][tx] = (hw < HWF) ? feats[((size_t)img * CF + c) * HWF + hw] : 0.f;
            }
            __syncthreads();
            #pragma unroll
            for (int i = 0; i < 4; ++i) {
                const int hw = hw0 + ty + 8 * i;
                if (hw < HWF)
                    featsT[((size_t)img * HWF + hw) * CF + c0 + tx] = f2bf(tile[tx][ty + 8 * i]);
            }
            __syncthreads();
        }
    } else if (blockIdx.x < 592) {
        const int bid = blockIdx.x - 528;
        const int kt = bid >> 3, nt = bid & 7;
        #pragma unroll
        for (int i = 0; i < 4; ++i)
            tile[ty + 8 * i][tx] = Wo[(size_t)(kt * 32 + ty + 8 * i) * HID + nt * 32 + tx];
        __syncthreads();
        #pragma unroll
        for (int i = 0; i < 4; ++i)
            WoT[(size_t)(nt * 32 + ty + 8 * i) * HID + kt * 32 + tx] = f2bf(tile[tx][ty + 8 * i]);
    } else {
        const int bid = blockIdx.x - 592;
        #pragma unroll
        for (int v = 0; v < 4; ++v) {
            const int idx = bid * 1024 + v * 256 + threadIdx.x;
            const int j = idx >> 8, k = idx & 255;
            WaT[idx] = (j < 24) ? f2bf(Wa[k * 24 + j]) : (unsigned short)0;
        }
    }
}

// ---------------- mid fallback: round-3 fused kernel ----------------
__global__ __launch_bounds__(512) void ca_fused3(
    const float* __restrict__ query, const float* __restrict__ query_pos,
    const float* __restrict__ rho,   const float* __restrict__ phi,
    const float* __restrict__ zz,    const unsigned short* __restrict__ featsT,
    const float* __restrict__ l2i,   const float* __restrict__ intervals,
    const float* __restrict__ pc_range, const float* __restrict__ img_size,
    const unsigned short* __restrict__ WaT, const float* __restrict__ ba,
    const unsigned short* __restrict__ WoT, const float* __restrict__ bo,
    float* __restrict__ out)
{
    __shared__ char  fab[16 * 512];
    __shared__ float awl[16][36];
    const int tid  = threadIdx.x;
    const int wave = tid >> 6;
    const int lane = tid & 63;
    const int l32  = lane & 31;
    const int r    = wave * 2 + (lane >> 5);
    const int base = blockIdx.x * 16;
    const int g    = base + r;
    const int b    = g >> 14;
    const int q    = g & (NQ - 1);
    const size_t qrow = ((size_t)q * BS + b) * HID;
    {
        const float4 a0 = *reinterpret_cast<const float4*>(&query[qrow + 8 * l32]);
        const float4 a1 = *reinterpret_cast<const float4*>(&query[qrow + 8 * l32 + 4]);
        const float4 p0 = *reinterpret_cast<const float4*>(&query_pos[qrow + 8 * l32]);
        const float4 p1 = *reinterpret_cast<const float4*>(&query_pos[qrow + 8 * l32 + 4]);
        uint4 u;
        u.x = ((unsigned)f2bf(a0.y + p0.y) << 16) | f2bf(a0.x + p0.x);
        u.y = ((unsigned)f2bf(a0.w + p0.w) << 16) | f2bf(a0.z + p0.z);
        u.z = ((unsigned)f2bf(a1.y + p1.y) << 16) | f2bf(a1.x + p1.x);
        u.w = ((unsigned)f2bf(a1.w + p1.w) << 16) | f2bf(a1.z + p1.z);
        *reinterpret_cast<uint4*>(fab + ((unsigned)(r * 512 + 16 * l32) ^ ((unsigned)(r & 7) << 4))) = u;
    }
    float gxs[NCAM], gys[NCAM];
    bool  msk[NCAM];
    {
        const float pc0 = pc_range[0], pc1 = pc_range[1];
        const float pc2 = pc_range[2], pc3 = pc_range[3];
        const float rr = rho[q] * pc0 + intervals[0] * 0.5f;
        const float pp = phi[q] * pc1 - 3.14159265358979323846f + intervals[1] * 0.5f;
        const float xx = rr * cosf(pp);
        const float yy = rr * sinf(pp);
        const float z  = zz[b * NQ + q] * (pc3 - pc2) + pc2;
        const float iw = img_size[0], ih = img_size[1];
        #pragma unroll
        for (int n = 0; n < NCAM; ++n) {
            const float* M = l2i + (b * NCAM + n) * 16;
            const float cx = M[0]*xx + M[1]*yy + M[2]*z  + M[3];
            const float cy = M[4]*xx + M[5]*yy + M[6]*z  + M[7];
            const float cz = M[8]*xx + M[9]*yy + M[10]*z + M[11];
            const float d  = fmaxf(cz, EPSV);
            const float gx = (cx / d / iw - 0.5f) * 2.0f;
            const float gy = (cy / d / ih - 0.5f) * 2.0f;
            msk[n] = (cz > EPSV) && (gx > -1.0f) && (gx < 1.0f)
                                 && (gy > -1.0f) && (gy < 1.0f);
            gxs[n] = gx; gys[n] = gy;
        }
    }
    if (l32 < NCAM)
        out[(size_t)NQ * BS * HID + ((size_t)b * NQ + q) * NCAM + l32] =
            msk[l32] ? 1.0f : 0.0f;
    __syncthreads();
    if (wave < 2) {
        const int arow = lane & 15;
        const int g4   = lane >> 4;
        float4v aw = {0.f,0.f,0.f,0.f};
        #pragma unroll
        for (int kk = 0; kk < 8; ++kk) {
            const int k0 = kk * 32 + g4 * 8;
            const short8v af = *reinterpret_cast<const short8v*>(
                fab + ((unsigned)(arow * 512 + k0 * 2) ^ ((unsigned)(arow & 7) << 4)));
            const short8v bw = *reinterpret_cast<const short8v*>(
                WaT + (size_t)(wave * 16 + arow) * HID + k0);
            aw = __builtin_amdgcn_mfma_f32_16x16x32_bf16(af, bw, aw, 0, 0, 0);
        }
        #pragma unroll
        for (int i = 0; i < 4; ++i)
            awl[g4 * 4 + i][wave * 16 + arow] = aw[i];
    }
    __syncthreads();
    float wsv[NCAM];
    {
        float sv = 0.f;
        if (l32 < 24) {
            const float x = awl[r][l32] + ba[l32];
            sv = 1.0f / (1.0f + __expf(-x));
        }
        sv += __shfl_xor(sv, 1);
        sv += __shfl_xor(sv, 2);
        #pragma unroll
        for (int n = 0; n < NCAM; ++n)
            wsv[n] = __shfl(sv, (lane & 32) + 4 * n);
    }
    float acc[8] = {0.f,0.f,0.f,0.f,0.f,0.f,0.f,0.f};
    for (int n = 0; n < NCAM; ++n) {
        if (msk[n]) {
            const float ixf = ((gxs[n] + 1.0f) * WF - 1.0f) * 0.5f;
            const float iyf = ((gys[n] + 1.0f) * HF - 1.0f) * 0.5f;
            const float x0f = floorf(ixf), y0f = floorf(iyf);
            const float fx = ixf - x0f, fy = iyf - y0f;
            const int x0 = (int)x0f, y0 = (int)y0f;
            const int   xs[4] = {x0, x0 + 1, x0,     x0 + 1};
            const int   ys[4] = {y0, y0,     y0 + 1, y0 + 1};
            const float wc[4] = {(1.f-fx)*(1.f-fy), fx*(1.f-fy),
                                 (1.f-fx)*fy,       fx*fy};
            const unsigned short* fb = featsT + (size_t)(b * NCAM + n) * HWF * CF + 8 * l32;
            #pragma unroll
            for (int c4 = 0; c4 < 4; ++c4) {
                const bool v = (xs[c4] >= 0) && (xs[c4] < WF) &&
                               (ys[c4] >= 0) && (ys[c4] < HF);
                const int xc = min(max(xs[c4], 0), WF - 1);
                const int yc = min(max(ys[c4], 0), HF - 1);
                const float wnv = wsv[n] * (v ? wc[c4] : 0.0f);
                const uint4 u = *reinterpret_cast<const uint4*>(fb + (size_t)(yc * WF + xc) * CF);
                acc[0] += wnv * bfLO(u.x); acc[1] += wnv * bfHI(u.x);
                acc[2] += wnv * bfLO(u.y); acc[3] += wnv * bfHI(u.y);
                acc[4] += wnv * bfLO(u.z); acc[5] += wnv * bfHI(u.z);
                acc[6] += wnv * bfLO(u.w); acc[7] += wnv * bfHI(u.w);
            }
        }
    }
    {
        uint4 u;
        u.x = ((unsigned)f2bf(acc[1]) << 16) | f2bf(acc[0]);
        u.y = ((unsigned)f2bf(acc[3]) << 16) | f2bf(acc[2]);
        u.z = ((unsigned)f2bf(acc[5]) << 16) | f2bf(acc[4]);
        u.w = ((unsigned)f2bf(acc[7]) << 16) | f2bf(acc[6]);
        *reinterpret_cast<uint4*>(fab + ((unsigned)(r * 512 + 16 * l32) ^ ((unsigned)(r & 7) << 4))) = u;
    }
    __syncthreads();
    const int colw = lane & 15;
    const int g4   = lane >> 4;
    #pragma unroll
    for (int t = 0; t < 2; ++t) {
        const int col = wave * 16 + t * 128 + colw;
        float4v dacc = {0.f,0.f,0.f,0.f};
        #pragma unroll
        for (int kk = 0; kk < 8; ++kk) {
            const int k0 = kk * 32 + g4 * 8;
            const short8v af = *reinterpret_cast<const short8v*>(
                fab + ((unsigned)(colw * 512 + k0 * 2) ^ ((unsigned)(colw & 7) << 4)));
            const short8v bw = *reinterpret_cast<const short8v*>(
                WoT + (size_t)col * HID + k0);
            dacc = __builtin_amdgcn_mfma_f32_16x16x32_bf16(af, bw, dacc, 0, 0, 0);
        }
        #pragma unroll
        for (int rg = 0; rg < 4; ++rg) {
            const int row = g4 * 4 + rg;
            const int gq = base + row;
            const int bq = gq >> 14, qq = gq & (NQ - 1);
            const size_t addr = ((size_t)qq * BS + bq) * HID + col;
            out[addr] = dacc[rg] + bo[col] + query[addr];
        }
    }
}

// ---------------- last-resort fallback (round-1, no workspace) ----------------
#define CHUNK 32
__global__ __launch_bounds__(512, 2) void ca_fused_fb(
    const float* __restrict__ query, const float* __restrict__ query_pos,
    const float* __restrict__ rho, const float* __restrict__ phi,
    const float* __restrict__ zz, const float* __restrict__ feats,
    const float* __restrict__ l2i, const float* __restrict__ intervals,
    const float* __restrict__ pc_range, const float* __restrict__ img_size,
    const float* __restrict__ Wa, const float* __restrict__ ba,
    const float* __restrict__ Wo, const float* __restrict__ bo,
    float* __restrict__ out)
{
    __shared__ float fa[8][HID];
    __shared__ float wolds[CHUNK][HID];
    const int tid  = threadIdx.x;
    const int wave = tid >> 6;
    const int lane = tid & 63;
    const int g    = blockIdx.x * 8 + wave;
    const int b    = g / NQ;
    const int q    = g - b * NQ;
    const size_t qrow = ((size_t)q * BS + b) * HID;
    {
        float qv[4];
        #pragma unroll
        for (int k = 0; k < 4; ++k) {
            const int h = lane + 64 * k;
            qv[k] = query[qrow + h] + query_pos[qrow + h];
        }
        const float pc0 = pc_range[0], pc1 = pc_range[1];
        const float pc2 = pc_range[2], pc3 = pc_range[3];
        const float r = rho[q] * pc0 + intervals[0] * 0.5f;
        const float p = phi[q] * pc1 - 3.14159265358979323846f + intervals[1] * 0.5f;
        const float xx = r * cosf(p);
        const float yy = r * sinf(p);
        const float z  = zz[b * NQ + q] * (pc3 - pc2) + pc2;
        const float iw = img_size[0], ih = img_size[1];
        float gxs[NCAM], gys[NCAM], wss[NCAM];
        bool  msk[NCAM];
        #pragma unroll
        for (int n = 0; n < NCAM; ++n) {
            const float* M = l2i + (b * NCAM + n) * 16;
            const float cx = M[0]*xx + M[1]*yy + M[2]*z  + M[3];
            const float cy = M[4]*xx + M[5]*yy + M[6]*z  + M[7];
            const float cz = M[8]*xx + M[9]*yy + M[10]*z + M[11];
            const float d  = fmaxf(cz, EPSV);
            const float gx = (cx / d / iw - 0.5f) * 2.0f;
            const float gy = (cy / d / ih - 0.5f) * 2.0f;
            msk[n] = (cz > EPSV) && (gx > -1.0f) && (gx < 1.0f)
                                 && (gy > -1.0f) && (gy < 1.0f);
            gxs[n] = gx; gys[n] = gy; wss[n] = 0.0f;
        }
        for (int n = 0; n < NCAM; ++n) {
            if (!msk[n]) continue;
            float s = 0.0f;
            #pragma unroll
            for (int pp = 0; pp < NPTS; ++pp) {
                const int j = n * NPTS + pp;
                float part = 0.0f;
                #pragma unroll
                for (int k = 0; k < 4; ++k)
                    part += qv[k] * Wa[(lane + 64 * k) * 24 + j];
                #pragma unroll
                for (int off = 32; off; off >>= 1)
                    part += __shfl_xor(part, off, 64);
                s += 1.0f / (1.0f + expf(-(part + ba[j])));
            }
            wss[n] = s;
        }
        if (lane < NCAM)
            out[(size_t)NQ * BS * HID + ((size_t)b * NQ + q) * NCAM + lane] =
                msk[lane] ? 1.0f : 0.0f;
        float acc[4] = {0.f,0.f,0.f,0.f};
        for (int n = 0; n < NCAM; ++n) {
            if (!msk[n]) continue;
            const float ixf = ((gxs[n] + 1.0f) * WF - 1.0f) * 0.5f;
            const float iyf = ((gys[n] + 1.0f) * HF - 1.0f) * 0.5f;
            const float x0f = floorf(ixf), y0f = floorf(iyf);
            const float fx = ixf - x0f, fy = iyf - y0f;
            const int x0 = (int)x0f, y0 = (int)y0f;
            const int   xs[4] = {x0, x0 + 1, x0,     x0 + 1};
            const int   ys[4] = {y0, y0,     y0 + 1, y0 + 1};
            const float wc[4] = {(1.f-fx)*(1.f-fy), fx*(1.f-fy),
                                 (1.f-fx)*fy,       fx*fy};
            int   offc[4];
            float wv[4];
            #pragma unroll
            for (int c4 = 0; c4 < 4; ++c4) {
                const bool v = (xs[c4] >= 0) && (xs[c4] < WF) &&
                               (ys[c4] >= 0) && (ys[c4] < HF);
                const int xc = min(max(xs[c4], 0), WF - 1);
                const int yc = min(max(ys[c4], 0), HF - 1);
                offc[c4] = yc * WF + xc;
                wv[c4]   = v ? wc[c4] : 0.0f;
            }
            const float wn = wss[n];
            const float* fbp = feats + (size_t)(b * NCAM + n) * CF * HWF;
            #pragma unroll
            for (int k = 0; k < 4; ++k) {
                const float* fc = fbp + (size_t)(lane + 64 * k) * HWF;
                const float sv = wv[0]*fc[offc[0]] + wv[1]*fc[offc[1]]
                               + wv[2]*fc[offc[2]] + wv[3]*fc[offc[3]];
                acc[k] += wn * sv;
            }
        }
        #pragma unroll
        for (int k = 0; k < 4; ++k)
            fa[wave][lane + 64 * k] = acc[k];
    }
    float racc[4] = {0.f,0.f,0.f,0.f};
    const int h0 = 4 * lane;
    for (int c0 = 0; c0 < HID; c0 += CHUNK) {
        __syncthreads();
        for (int i = tid; i < CHUNK * HID; i += 512)
            wolds[i >> 8][i & 255] = Wo[(size_t)(c0 + (i >> 8)) * HID + (i & 255)];
        __syncthreads();
        #pragma unroll 8
        for (int c = 0; c < CHUNK; ++c) {
            const float fav = fa[wave][c0 + c];
            const float4 wv4 = *reinterpret_cast<const float4*>(&wolds[c][h0]);
            racc[0] += fav * wv4.x;
            racc[1] += fav * wv4.y;
            racc[2] += fav * wv4.z;
            racc[3] += fav * wv4.w;
        }
    }
    float4 o;
    o.x = racc[0] + bo[h0 + 0] + query[qrow + h0 + 0];
    o.y = racc[1] + bo[h0 + 1] + query[qrow + h0 + 1];
    o.z = racc[2] + bo[h0 + 2] + query[qrow + h0 + 2];
    o.w = racc[3] + bo[h0 + 3] + query[qrow + h0 + 3];
    *reinterpret_cast<float4*>(&out[qrow + h0]) = o;
}

extern "C" void kernel_launch(void* const* d_in, const int* in_sizes, int n_in,
                              void* d_out, int out_size, void* d_ws, size_t ws_size,
                              hipStream_t stream) {
    const float* query     = (const float*)d_in[0];
    const float* query_pos = (const float*)d_in[1];
    const float* rho       = (const float*)d_in[2];
    const float* phi       = (const float*)d_in[3];
    const float* zz        = (const float*)d_in[4];
    const float* feats     = (const float*)d_in[5];
    const float* l2i       = (const float*)d_in[6];
    const float* intervals = (const float*)d_in[7];
    const float* pc_range  = (const float*)d_in[8];
    const float* img_size  = (const float*)d_in[9];
    const float* Wa        = (const float*)d_in[10];
    const float* ba        = (const float*)d_in[11];
    const float* Wo        = (const float*)d_in[12];
    const float* bo        = (const float*)d_in[13];
    float* out = (float*)d_out;

    const size_t featsT_bytes = (size_t)NIMG * HWF * CF * 2;   // 8,601,600
    const size_t woT_bytes    = (size_t)HID * HID * 2;         // 131,072
    const size_t waT_bytes    = (size_t)32 * HID * 2;          // 16,384
    const size_t ws_bytes     = (size_t)BS * NQ * 8 * 4;       // 1,048,576
    const size_t gxy_bytes    = (size_t)BS * NQ * 12 * 4;      // 1,572,864
    const size_t need_small   = featsT_bytes + woT_bytes + waT_bytes;
    const size_t need_full    = featsT_bytes + woT_bytes + ws_bytes + gxy_bytes;

    if (ws_size >= need_full) {
        unsigned short* featsT = (unsigned short*)d_ws;
        unsigned short* WoT    = (unsigned short*)((char*)d_ws + featsT_bytes);
        float*          wsb    = (float*)((char*)d_ws + featsT_bytes + woT_bytes);
        float*          gxy    = (float*)((char*)d_ws + featsT_bytes + woT_bytes + ws_bytes);
        prep_aw<<<1872, 256, 0, stream>>>(feats, Wo, Wa, query, query_pos, ba,
                                          rho, phi, zz, l2i, intervals, pc_range,
                                          img_size, featsT, WoT, wsb, gxy, out);
        ca_main15<<<2048, 512, 0, stream>>>(query, featsT, wsb, gxy, WoT, bo, out);
    } else if (ws_size >= need_small) {
        unsigned short* featsT = (unsigned short*)d_ws;
        unsigned short* WoT    = (unsigned short*)((char*)d_ws + featsT_bytes);
        unsigned short* WaT    = (unsigned short*)((char*)d_ws + featsT_bytes + woT_bytes);
        prep_all<<<600, 256, 0, stream>>>(feats, Wo, Wa, featsT, WoT, WaT);
        ca_fused3<<<2048, 512, 0, stream>>>(query, query_pos, rho, phi, zz,
                                            featsT, l2i, intervals, pc_range,
                                            img_size, WaT, ba, WoT, bo, out);
    } else {
        ca_fused_fb<<<(BS * NQ) / 8, 512, 0, stream>>>(query, query_pos, rho, phi, zz,
                                                       feats, l2i, intervals, pc_range,
                                                       img_size, Wa, ba, Wo, bo, out);
    }
}

// Round 16
// 65.597 us; speedup vs baseline: 1.1690x; 1.1690x over previous
//
#include <hip/hip_runtime.h>
#include <hip/hip_bf16.h>
#include <math.h>

#define NQ    16384
#define BS    2
#define HID   256
#define NCAM  6
#define NPTS  4
#define CF    256
#define HF    28
#define WF    50
#define HWF   (HF*WF)
#define NIMG  (BS*NCAM)
#define EPSV  1e-5f

typedef __attribute__((ext_vector_type(8))) short short8v;
typedef __attribute__((ext_vector_type(4))) float float4v;

__device__ __forceinline__ unsigned short f2bf(float f) {
    unsigned u = __float_as_uint(f);
    u += 0x7fffu + ((u >> 16) & 1u);
    return (unsigned short)(u >> 16);
}
__device__ __forceinline__ unsigned pkbf(float lo, float hi) {
    __hip_bfloat162 h = __float22bfloat162_rn(float2{lo, hi});
    return *reinterpret_cast<unsigned*>(&h);
}
__device__ __forceinline__ float bfLO(unsigned u) { return __uint_as_float(u << 16); }
__device__ __forceinline__ float bfHI(unsigned u) { return __uint_as_float(u & 0xffff0000u); }

// ---------------- K1: pre-pass: featsT + WoT + aw + geometry (round-12 proven) ----------------
__global__ __launch_bounds__(256) void prep_aw(
    const float* __restrict__ feats, const float* __restrict__ Wo,
    const float* __restrict__ Wa,    const float* __restrict__ query,
    const float* __restrict__ query_pos, const float* __restrict__ ba,
    const float* __restrict__ rho,   const float* __restrict__ phi,
    const float* __restrict__ zz,    const float* __restrict__ l2i,
    const float* __restrict__ intervals, const float* __restrict__ pc_range,
    const float* __restrict__ img_size,
    unsigned short* __restrict__ featsT, unsigned short* __restrict__ WoT,
    float* __restrict__ ws, float* __restrict__ gxy, float* __restrict__ out)
{
    __shared__ __align__(16) char smem[32 * 264 * 2];   // 16896 B

    const int tx = threadIdx.x & 31;
    const int ty = threadIdx.x >> 5;
    if (blockIdx.x < 528) {
        float (*tile)[33] = reinterpret_cast<float(*)[33]>(smem);
        const int img = blockIdx.x / 44;
        const int hw0 = (blockIdx.x % 44) * 32;
        for (int ct = 0; ct < 8; ++ct) {
            const int c0 = ct * 32;
            #pragma unroll
            for (int i = 0; i < 4; ++i) {
                const int c  = c0 + ty + 8 * i;
                const int hw = hw0 + tx;
                tile[ty + 8 * i][tx] = (hw < HWF) ? feats[((size_t)img * CF + c) * HWF + hw] : 0.f;
            }
            __syncthreads();
            #pragma unroll
            for (int i = 0; i < 4; ++i) {
                const int hw = hw0 + ty + 8 * i;
                if (hw < HWF)
                    featsT[((size_t)img * HWF + hw) * CF + c0 + tx] = f2bf(tile[tx][ty + 8 * i]);
            }
            __syncthreads();
        }
    } else if (blockIdx.x < 592) {
        float (*tile)[33] = reinterpret_cast<float(*)[33]>(smem);
        const int bid = blockIdx.x - 528;
        const int kt = bid >> 3, nt = bid & 7;
        #pragma unroll
        for (int i = 0; i < 4; ++i)
            tile[ty + 8 * i][tx] = Wo[(size_t)(kt * 32 + ty + 8 * i) * HID + nt * 32 + tx];
        __syncthreads();
        #pragma unroll
        for (int i = 0; i < 4; ++i)
            WoT[(size_t)(nt * 32 + ty + 8 * i) * HID + kt * 32 + tx] = f2bf(tile[tx][ty + 8 * i]);
    } else if (blockIdx.x < 1104) {
        unsigned short (*waL)[264] = reinterpret_cast<unsigned short(*)[264]>(smem);
        #pragma unroll
        for (int s = 0; s < 32; ++s)
            waL[s][threadIdx.x] = (s < 24) ? f2bf(Wa[threadIdx.x * 24 + s]) : (unsigned short)0;
        __syncthreads();

        const int bid  = blockIdx.x - 592;
        const int wave = threadIdx.x >> 6;
        const int lane = threadIdx.x & 63;
        const int arow = lane & 15;
        const int g4   = lane >> 4;
        const int g0   = (bid * 4 + wave) * 16;
        const int ga   = g0 + arow;
        const int bb   = ga >> 14;
        const int qq   = ga & (NQ - 1);
        const float* qp1 = query     + ((size_t)qq * BS + bb) * HID;
        const float* qp2 = query_pos + ((size_t)qq * BS + bb) * HID;

        float4v aw0 = {0.f,0.f,0.f,0.f}, aw1 = {0.f,0.f,0.f,0.f};
        #pragma unroll
        for (int kk = 0; kk < 8; ++kk) {
            const int k0 = kk * 32 + g4 * 8;
            const float4 a0 = *reinterpret_cast<const float4*>(qp1 + k0);
            const float4 a1 = *reinterpret_cast<const float4*>(qp1 + k0 + 4);
            const float4 p0 = *reinterpret_cast<const float4*>(qp2 + k0);
            const float4 p1 = *reinterpret_cast<const float4*>(qp2 + k0 + 4);
            union { uint4 u; short8v s; } af;
            af.u.x = pkbf(a0.x + p0.x, a0.y + p0.y);
            af.u.y = pkbf(a0.z + p0.z, a0.w + p0.w);
            af.u.z = pkbf(a1.x + p1.x, a1.y + p1.y);
            af.u.w = pkbf(a1.z + p1.z, a1.w + p1.w);
            const short8v b0 = *reinterpret_cast<const short8v*>(&waL[arow][k0]);
            const short8v b1 = *reinterpret_cast<const short8v*>(&waL[16 + arow][k0]);
            aw0 = __builtin_amdgcn_mfma_f32_16x16x32_bf16(af.s, b0, aw0, 0, 0, 0);
            aw1 = __builtin_amdgcn_mfma_f32_16x16x32_bf16(af.s, b1, aw1, 0, 0, 0);
        }
        const float ba0 = ba[arow];
        const float ba1 = (arow < 8) ? ba[16 + arow] : 0.f;
        #pragma unroll
        for (int i = 0; i < 4; ++i) {
            float s0 = 1.0f / (1.0f + __expf(-(aw0[i] + ba0)));
            float s1 = (arow < 8) ? 1.0f / (1.0f + __expf(-(aw1[i] + ba1))) : 0.f;
            s0 += __shfl_xor(s0, 1);  s0 += __shfl_xor(s0, 2);
            s1 += __shfl_xor(s1, 1);  s1 += __shfl_xor(s1, 2);
            if ((arow & 3) == 0) {
                const int gq = g0 + g4 * 4 + i;
                ws[(size_t)gq * 8 + (arow >> 2)] = s0;
                if (arow < 8)
                    ws[(size_t)gq * 8 + 4 + (arow >> 2)] = s1;
            }
        }
    } else {
        const int pair = (blockIdx.x - 1104) * 256 + threadIdx.x;   // 0..196607
        const int gq   = pair / 6;
        const int cam  = pair - gq * 6;
        const int bb   = gq >> 14;
        const int qn   = gq & (NQ - 1);
        const float pc0 = pc_range[0], pc1 = pc_range[1];
        const float pc2 = pc_range[2], pc3 = pc_range[3];
        const float rr = rho[qn] * pc0 + intervals[0] * 0.5f;
        const float pp = phi[qn] * pc1 - 3.14159265358979323846f + intervals[1] * 0.5f;
        const float xx = rr * cosf(pp);
        const float yy = rr * sinf(pp);
        const float z  = zz[bb * NQ + qn] * (pc3 - pc2) + pc2;
        const float* M = l2i + (bb * NCAM + cam) * 16;
        const float cx = M[0]*xx + M[1]*yy + M[2]*z  + M[3];
        const float cy = M[4]*xx + M[5]*yy + M[6]*z  + M[7];
        const float cz = M[8]*xx + M[9]*yy + M[10]*z + M[11];
        const float d  = fmaxf(cz, EPSV);
        const float gx = (cx / d / img_size[0] - 0.5f) * 2.0f;
        const float gy = (cy / d / img_size[1] - 0.5f) * 2.0f;
        const bool  mk = (cz > EPSV) && (gx > -1.0f) && (gx < 1.0f)
                                     && (gy > -1.0f) && (gy < 1.0f);
        gxy[(size_t)gq * 12 + cam * 2]     = mk ? gx : -3.0f;
        gxy[(size_t)gq * 12 + cam * 2 + 1] = mk ? gy : 0.0f;
        out[(size_t)NQ * BS * HID + pair]  = mk ? 1.0f : 0.0f;
    }
}

// ---------------- K2: main kernel — XCD-mapped, asm-pipelined Phase B (round-14 champion) ----------------
__global__ __launch_bounds__(512, 4) void ca_main14(
    const float* __restrict__ query, const unsigned short* __restrict__ featsT,
    const float* __restrict__ ws,    const float* __restrict__ gxy,
    const unsigned short* __restrict__ WoT, const float* __restrict__ bo,
    float* __restrict__ out)
{
    __shared__ char fab[16 * 512];   // bf16 [16][256] fa, XOR-swizzled

    const int tid  = threadIdx.x;
    const int wave = tid >> 6;
    const int lane = tid & 63;
    const int l32  = lane & 31;
    const int r    = wave * 2 + (lane >> 5);

    // XCD-aware block->query mapping: XCDs 0-3 serve batch 0, XCDs 4-7 batch 1
    const int bid  = blockIdx.x;
    const int xg   = (bid & 7) >> 2;                   // batch
    const int idx  = (bid & 3) + ((bid >> 3) << 2);    // 0..1023
    const int base = (xg << 14) + idx * 16;            // first query id of block
    const int b    = xg;
    const int g    = base + r;

    // early independent coalesced loads (whole front-end state)
    const float wsn = ws[(size_t)g * 8 + (l32 & 7)];
    const float gv  = (l32 < 12) ? gxy[(size_t)g * 12 + l32] : 0.f;

    float gxs[NCAM], gys[NCAM], wsv[NCAM];
    bool  msk[NCAM];
    #pragma unroll
    for (int n = 0; n < NCAM; ++n) {
        gxs[n] = __shfl(gv, (lane & 32) + 2 * n);
        gys[n] = __shfl(gv, (lane & 32) + 2 * n + 1);
        msk[n] = gxs[n] > -2.0f;
        wsv[n] = msk[n] ? __shfl(wsn, (lane & 32) + n) : 0.f;
    }

    // ---- masked bilinear gather (8 ch/lane), per-camera asm-batched loads ----
    float acc[8] = {0.f,0.f,0.f,0.f,0.f,0.f,0.f,0.f};
    for (int n = 0; n < NCAM; ++n) {
        if (msk[n]) {
            const float ixf = ((gxs[n] + 1.0f) * WF - 1.0f) * 0.5f;
            const float iyf = ((gys[n] + 1.0f) * HF - 1.0f) * 0.5f;
            const float x0f = floorf(ixf), y0f = floorf(iyf);
            const float fx = ixf - x0f, fy = iyf - y0f;
            const int x0 = (int)x0f, y0 = (int)y0f;
            const int   xs[4] = {x0, x0 + 1, x0,     x0 + 1};
            const int   ys[4] = {y0, y0,     y0 + 1, y0 + 1};
            const float wc[4] = {(1.f-fx)*(1.f-fy), fx*(1.f-fy),
                                 (1.f-fx)*fy,       fx*fy};
            const unsigned short* fb = featsT + (size_t)(b * NCAM + n) * HWF * CF + 8 * l32;
            uint4 u[4];
            float w[4];
            #pragma unroll
            for (int c4 = 0; c4 < 4; ++c4) {
                const bool v = (xs[c4] >= 0) && (xs[c4] < WF) &&
                               (ys[c4] >= 0) && (ys[c4] < HF);
                const int xc = min(max(xs[c4], 0), WF - 1);
                const int yc = min(max(ys[c4], 0), HF - 1);
                const unsigned short* ap = fb + (size_t)(yc * WF + xc) * CF;
                asm volatile("global_load_dwordx4 %0, %1, off"
                             : "=v"(u[c4]) : "v"(ap));
                w[c4] = wsv[n] * (v ? wc[c4] : 0.0f);
            }
            asm volatile("s_waitcnt vmcnt(0)" ::: "memory");
            __builtin_amdgcn_sched_barrier(0);
            #pragma unroll
            for (int c4 = 0; c4 < 4; ++c4) {
                acc[0] += w[c4] * bfLO(u[c4].x); acc[1] += w[c4] * bfHI(u[c4].x);
                acc[2] += w[c4] * bfLO(u[c4].y); acc[3] += w[c4] * bfHI(u[c4].y);
                acc[4] += w[c4] * bfLO(u[c4].z); acc[5] += w[c4] * bfHI(u[c4].z);
                acc[6] += w[c4] * bfLO(u[c4].w); acc[7] += w[c4] * bfHI(u[c4].w);
            }
        }
    }

    // ---- fa row -> bf16 swizzled LDS (packed cvt); single barrier ----
    {
        uint4 u;
        u.x = pkbf(acc[0], acc[1]);
        u.y = pkbf(acc[2], acc[3]);
        u.z = pkbf(acc[4], acc[5]);
        u.w = pkbf(acc[6], acc[7]);
        *reinterpret_cast<uint4*>(fab + ((unsigned)(r * 512 + 16 * l32) ^ ((unsigned)(r & 7) << 4))) = u;
    }
    __syncthreads();

    // ---- Phase B: O[16][256] = fa @ Wo; asm-forced B prefetch, one wait per tile ----
    const int colw = lane & 15;
    const int g4   = lane >> 4;
    float4v dacc[2];
    #pragma unroll
    for (int t = 0; t < 2; ++t) {
        const int col = wave * 16 + t * 128 + colw;
        const unsigned short* bp = WoT + (size_t)col * HID + g4 * 8;
        uint4 bw[8];
        #pragma unroll
        for (int i = 0; i < 8; ++i)
            asm volatile("global_load_dwordx4 %0, %1, off"
                         : "=v"(bw[i]) : "v"(bp + (size_t)i * 32));
        short8v af[8];
        #pragma unroll
        for (int kk = 0; kk < 8; ++kk)
            af[kk] = *reinterpret_cast<const short8v*>(
                fab + ((unsigned)(colw * 512 + (kk * 32 + g4 * 8) * 2) ^ ((unsigned)(colw & 7) << 4)));
        asm volatile("s_waitcnt vmcnt(0)" ::: "memory");
        __builtin_amdgcn_sched_barrier(0);
        float4v d = {0.f,0.f,0.f,0.f};
        #pragma unroll
        for (int kk = 0; kk < 8; ++kk) {
            union { uint4 u; short8v s; } bu; bu.u = bw[kk];
            d = __builtin_amdgcn_mfma_f32_16x16x32_bf16(af[kk], bu.s, d, 0, 0, 0);
        }
        dacc[t] = d;
    }
    #pragma unroll
    for (int t = 0; t < 2; ++t) {
        const int col = wave * 16 + t * 128 + colw;
        const float boc = bo[col];
        #pragma unroll
        for (int rg = 0; rg < 4; ++rg) {
            const int row = g4 * 4 + rg;
            const int gq = base + row;
            const int bq = gq >> 14, qq = gq & (NQ - 1);
            const size_t addr = ((size_t)qq * BS + bq) * HID + col;
            out[addr] = dacc[t][rg] + boc + query[addr];
        }
    }
}

// ---------------- fallback prep (with WaT, for ca_fused3 path) ----------------
__global__ __launch_bounds__(256) void prep_all(
    const float* __restrict__ feats, const float* __restrict__ Wo,
    const float* __restrict__ Wa, unsigned short* __restrict__ featsT,
    unsigned short* __restrict__ WoT, unsigned short* __restrict__ WaT)
{
    __shared__ float tile[32][33];
    const int tx = threadIdx.x & 31;
    const int ty = threadIdx.x >> 5;
    if (blockIdx.x < 528) {
        const int img = blockIdx.x / 44;
        const int hw0 = (blockIdx.x % 44) * 32;
        for (int ct = 0; ct < 8; ++ct) {
            const int c0 = ct * 32;
            #pragma unroll
            for (int i = 0; i < 4; ++i) {
                const int c  = c0 + ty + 8 * i;
                const int hw = hw0 + tx;
                tile[ty + 8 * i][tx] = (hw < HWF) ? feats[((size_t)img * CF + c) * HWF + hw] : 0.f;
            }
            __syncthreads();
            #pragma unroll
            for (int i = 0; i < 4; ++i) {
                const int hw = hw0 + ty + 8 * i;
                if (hw < HWF)
                    featsT[((size_t)img * HWF + hw) * CF + c0 + tx] = f2bf(tile[tx][ty + 8 * i]);
            }
            __syncthreads();
        }
    } else if (blockIdx.x < 592) {
        const int bid = blockIdx.x - 528;
        const int kt = bid >> 3, nt = bid & 7;
        #pragma unroll
        for (int i = 0; i < 4; ++i)
            tile[ty + 8 * i][tx] = Wo[(size_t)(kt * 32 + ty + 8 * i) * HID + nt * 32 + tx];
        __syncthreads();
        #pragma unroll
        for (int i = 0; i < 4; ++i)
            WoT[(size_t)(nt * 32 + ty + 8 * i) * HID + kt * 32 + tx] = f2bf(tile[tx][ty + 8 * i]);
    } else {
        const int bid = blockIdx.x - 592;
        #pragma unroll
        for (int v = 0; v < 4; ++v) {
            const int idx = bid * 1024 + v * 256 + threadIdx.x;
            const int j = idx >> 8, k = idx & 255;
            WaT[idx] = (j < 24) ? f2bf(Wa[k * 24 + j]) : (unsigned short)0;
        }
    }
}

// ---------------- mid fallback: round-3 fused kernel ----------------
__global__ __launch_bounds__(512) void ca_fused3(
    const float* __restrict__ query, const float* __restrict__ query_pos,
    const float* __restrict__ rho,   const float* __restrict__ phi,
    const float* __restrict__ zz,    const unsigned short* __restrict__ featsT,
    const float* __restrict__ l2i,   const float* __restrict__ intervals,
    const float* __restrict__ pc_range, const float* __restrict__ img_size,
    const unsigned short* __restrict__ WaT, const float* __restrict__ ba,
    const unsigned short* __restrict__ WoT, const float* __restrict__ bo,
    float* __restrict__ out)
{
    __shared__ char  fab[16 * 512];
    __shared__ float awl[16][36];
    const int tid  = threadIdx.x;
    const int wave = tid >> 6;
    const int lane = tid & 63;
    const int l32  = lane & 31;
    const int r    = wave * 2 + (lane >> 5);
    const int base = blockIdx.x * 16;
    const int g    = base + r;
    const int b    = g >> 14;
    const int q    = g & (NQ - 1);
    const size_t qrow = ((size_t)q * BS + b) * HID;
    {
        const float4 a0 = *reinterpret_cast<const float4*>(&query[qrow + 8 * l32]);
        const float4 a1 = *reinterpret_cast<const float4*>(&query[qrow + 8 * l32 + 4]);
        const float4 p0 = *reinterpret_cast<const float4*>(&query_pos[qrow + 8 * l32]);
        const float4 p1 = *reinterpret_cast<const float4*>(&query_pos[qrow + 8 * l32 + 4]);
        uint4 u;
        u.x = ((unsigned)f2bf(a0.y + p0.y) << 16) | f2bf(a0.x + p0.x);
        u.y = ((unsigned)f2bf(a0.w + p0.w) << 16) | f2bf(a0.z + p0.z);
        u.z = ((unsigned)f2bf(a1.y + p1.y) << 16) | f2bf(a1.x + p1.x);
        u.w = ((unsigned)f2bf(a1.w + p1.w) << 16) | f2bf(a1.z + p1.z);
        *reinterpret_cast<uint4*>(fab + ((unsigned)(r * 512 + 16 * l32) ^ ((unsigned)(r & 7) << 4))) = u;
    }
    float gxs[NCAM], gys[NCAM];
    bool  msk[NCAM];
    {
        const float pc0 = pc_range[0], pc1 = pc_range[1];
        const float pc2 = pc_range[2], pc3 = pc_range[3];
        const float rr = rho[q] * pc0 + intervals[0] * 0.5f;
        const float pp = phi[q] * pc1 - 3.14159265358979323846f + intervals[1] * 0.5f;
        const float xx = rr * cosf(pp);
        const float yy = rr * sinf(pp);
        const float z  = zz[b * NQ + q] * (pc3 - pc2) + pc2;
        const float iw = img_size[0], ih = img_size[1];
        #pragma unroll
        for (int n = 0; n < NCAM; ++n) {
            const float* M = l2i + (b * NCAM + n) * 16;
            const float cx = M[0]*xx + M[1]*yy + M[2]*z  + M[3];
            const float cy = M[4]*xx + M[5]*yy + M[6]*z  + M[7];
            const float cz = M[8]*xx + M[9]*yy + M[10]*z + M[11];
            const float d  = fmaxf(cz, EPSV);
            const float gx = (cx / d / iw - 0.5f) * 2.0f;
            const float gy = (cy / d / ih - 0.5f) * 2.0f;
            msk[n] = (cz > EPSV) && (gx > -1.0f) && (gx < 1.0f)
                                 && (gy > -1.0f) && (gy < 1.0f);
            gxs[n] = gx; gys[n] = gy;
        }
    }
    if (l32 < NCAM)
        out[(size_t)NQ * BS * HID + ((size_t)b * NQ + q) * NCAM + l32] =
            msk[l32] ? 1.0f : 0.0f;
    __syncthreads();
    if (wave < 2) {
        const int arow = lane & 15;
        const int g4   = lane >> 4;
        float4v aw = {0.f,0.f,0.f,0.f};
        #pragma unroll
        for (int kk = 0; kk < 8; ++kk) {
            const int k0 = kk * 32 + g4 * 8;
            const short8v af = *reinterpret_cast<const short8v*>(
                fab + ((unsigned)(arow * 512 + k0 * 2) ^ ((unsigned)(arow & 7) << 4)));
            const short8v bw = *reinterpret_cast<const short8v*>(
                WaT + (size_t)(wave * 16 + arow) * HID + k0);
            aw = __builtin_amdgcn_mfma_f32_16x16x32_bf16(af, bw, aw, 0, 0, 0);
        }
        #pragma unroll
        for (int i = 0; i < 4; ++i)
            awl[g4 * 4 + i][wave * 16 + arow] = aw[i];
    }
    __syncthreads();
    float wsv[NCAM];
    {
        float sv = 0.f;
        if (l32 < 24) {
            const float x = awl[r][l32] + ba[l32];
            sv = 1.0f / (1.0f + __expf(-x));
        }
        sv += __shfl_xor(sv, 1);
        sv += __shfl_xor(sv, 2);
        #pragma unroll
        for (int n = 0; n < NCAM; ++n)
            wsv[n] = __shfl(sv, (lane & 32) + 4 * n);
    }
    float acc[8] = {0.f,0.f,0.f,0.f,0.f,0.f,0.f,0.f};
    for (int n = 0; n < NCAM; ++n) {
        if (msk[n]) {
            const float ixf = ((gxs[n] + 1.0f) * WF - 1.0f) * 0.5f;
            const float iyf = ((gys[n] + 1.0f) * HF - 1.0f) * 0.5f;
            const float x0f = floorf(ixf), y0f = floorf(iyf);
            const float fx = ixf - x0f, fy = iyf - y0f;
            const int x0 = (int)x0f, y0 = (int)y0f;
            const int   xs[4] = {x0, x0 + 1, x0,     x0 + 1};
            const int   ys[4] = {y0, y0,     y0 + 1, y0 + 1};
            const float wc[4] = {(1.f-fx)*(1.f-fy), fx*(1.f-fy),
                                 (1.f-fx)*fy,       fx*fy};
            const unsigned short* fb = featsT + (size_t)(b * NCAM + n) * HWF * CF + 8 * l32;
            #pragma unroll
            for (int c4 = 0; c4 < 4; ++c4) {
                const bool v = (xs[c4] >= 0) && (xs[c4] < WF) &&
                               (ys[c4] >= 0) && (ys[c4] < HF);
                const int xc = min(max(xs[c4], 0), WF - 1);
                const int yc = min(max(ys[c4], 0), HF - 1);
                const float wnv = wsv[n] * (v ? wc[c4] : 0.0f);
                const uint4 u = *reinterpret_cast<const uint4*>(fb + (size_t)(yc * WF + xc) * CF);
                acc[0] += wnv * bfLO(u.x); acc[1] += wnv * bfHI(u.x);
                acc[2] += wnv * bfLO(u.y); acc[3] += wnv * bfHI(u.y);
                acc[4] += wnv * bfLO(u.z); acc[5] += wnv * bfHI(u.z);
                acc[6] += wnv * bfLO(u.w); acc[7] += wnv * bfHI(u.w);
            }
        }
    }
    {
        uint4 u;
        u.x = ((unsigned)f2bf(acc[1]) << 16) | f2bf(acc[0]);
        u.y = ((unsigned)f2bf(acc[3]) << 16) | f2bf(acc[2]);
        u.z = ((unsigned)f2bf(acc[5]) << 16) | f2bf(acc[4]);
        u.w = ((unsigned)f2bf(acc[7]) << 16) | f2bf(acc[6]);
        *reinterpret_cast<uint4*>(fab + ((unsigned)(r * 512 + 16 * l32) ^ ((unsigned)(r & 7) << 4))) = u;
    }
    __syncthreads();
    const int colw = lane & 15;
    const int g4   = lane >> 4;
    #pragma unroll
    for (int t = 0; t < 2; ++t) {
        const int col = wave * 16 + t * 128 + colw;
        float4v dacc = {0.f,0.f,0.f,0.f};
        #pragma unroll
        for (int kk = 0; kk < 8; ++kk) {
            const int k0 = kk * 32 + g4 * 8;
            const short8v af = *reinterpret_cast<const short8v*>(
                fab + ((unsigned)(colw * 512 + k0 * 2) ^ ((unsigned)(colw & 7) << 4)));
            const short8v bw = *reinterpret_cast<const short8v*>(
                WoT + (size_t)col * HID + k0);
            dacc = __builtin_amdgcn_mfma_f32_16x16x32_bf16(af, bw, dacc, 0, 0, 0);
        }
        #pragma unroll
        for (int rg = 0; rg < 4; ++rg) {
            const int row = g4 * 4 + rg;
            const int gq = base + row;
            const int bq = gq >> 14, qq = gq & (NQ - 1);
            const size_t addr = ((size_t)qq * BS + bq) * HID + col;
            out[addr] = dacc[rg] + bo[col] + query[addr];
        }
    }
}

// ---------------- last-resort fallback (round-1, no workspace) ----------------
#define CHUNK 32
__global__ __launch_bounds__(512, 2) void ca_fused_fb(
    const float* __restrict__ query, const float* __restrict__ query_pos,
    const float* __restrict__ rho, const float* __restrict__ phi,
    const float* __restrict__ zz, const float* __restrict__ feats,
    const float* __restrict__ l2i, const float* __restrict__ intervals,
    const float* __restrict__ pc_range, const float* __restrict__ img_size,
    const float* __restrict__ Wa, const float* __restrict__ ba,
    const float* __restrict__ Wo, const float* __restrict__ bo,
    float* __restrict__ out)
{
    __shared__ float fa[8][HID];
    __shared__ float wolds[CHUNK][HID];
    const int tid  = threadIdx.x;
    const int wave = tid >> 6;
    const int lane = tid & 63;
    const int g    = blockIdx.x * 8 + wave;
    const int b    = g / NQ;
    const int q    = g - b * NQ;
    const size_t qrow = ((size_t)q * BS + b) * HID;
    {
        float qv[4];
        #pragma unroll
        for (int k = 0; k < 4; ++k) {
            const int h = lane + 64 * k;
            qv[k] = query[qrow + h] + query_pos[qrow + h];
        }
        const float pc0 = pc_range[0], pc1 = pc_range[1];
        const float pc2 = pc_range[2], pc3 = pc_range[3];
        const float r = rho[q] * pc0 + intervals[0] * 0.5f;
        const float p = phi[q] * pc1 - 3.14159265358979323846f + intervals[1] * 0.5f;
        const float xx = r * cosf(p);
        const float yy = r * sinf(p);
        const float z  = zz[b * NQ + q] * (pc3 - pc2) + pc2;
        const float iw = img_size[0], ih = img_size[1];
        float gxs[NCAM], gys[NCAM], wss[NCAM];
        bool  msk[NCAM];
        #pragma unroll
        for (int n = 0; n < NCAM; ++n) {
            const float* M = l2i + (b * NCAM + n) * 16;
            const float cx = M[0]*xx + M[1]*yy + M[2]*z  + M[3];
            const float cy = M[4]*xx + M[5]*yy + M[6]*z  + M[7];
            const float cz = M[8]*xx + M[9]*yy + M[10]*z + M[11];
            const float d  = fmaxf(cz, EPSV);
            const float gx = (cx / d / iw - 0.5f) * 2.0f;
            const float gy = (cy / d / ih - 0.5f) * 2.0f;
            msk[n] = (cz > EPSV) && (gx > -1.0f) && (gx < 1.0f)
                                 && (gy > -1.0f) && (gy < 1.0f);
            gxs[n] = gx; gys[n] = gy; wss[n] = 0.0f;
        }
        for (int n = 0; n < NCAM; ++n) {
            if (!msk[n]) continue;
            float s = 0.0f;
            #pragma unroll
            for (int pp = 0; pp < NPTS; ++pp) {
                const int j = n * NPTS + pp;
                float part = 0.0f;
                #pragma unroll
                for (int k = 0; k < 4; ++k)
                    part += qv[k] * Wa[(lane + 64 * k) * 24 + j];
                #pragma unroll
                for (int off = 32; off; off >>= 1)
                    part += __shfl_xor(part, off, 64);
                s += 1.0f / (1.0f + expf(-(part + ba[j])));
            }
            wss[n] = s;
        }
        if (lane < NCAM)
            out[(size_t)NQ * BS * HID + ((size_t)b * NQ + q) * NCAM + lane] =
                msk[lane] ? 1.0f : 0.0f;
        float acc[4] = {0.f,0.f,0.f,0.f};
        for (int n = 0; n < NCAM; ++n) {
            if (!msk[n]) continue;
            const float ixf = ((gxs[n] + 1.0f) * WF - 1.0f) * 0.5f;
            const float iyf = ((gys[n] + 1.0f) * HF - 1.0f) * 0.5f;
            const float x0f = floorf(ixf), y0f = floorf(iyf);
            const float fx = ixf - x0f, fy = iyf - y0f;
            const int x0 = (int)x0f, y0 = (int)y0f;
            const int   xs[4] = {x0, x0 + 1, x0,     x0 + 1};
            const int   ys[4] = {y0, y0,     y0 + 1, y0 + 1};
            const float wc[4] = {(1.f-fx)*(1.f-fy), fx*(1.f-fy),
                                 (1.f-fx)*fy,       fx*fy};
            int   offc[4];
            float wv[4];
            #pragma unroll
            for (int c4 = 0; c4 < 4; ++c4) {
                const bool v = (xs[c4] >= 0) && (xs[c4] < WF) &&
                               (ys[c4] >= 0) && (ys[c4] < HF);
                const int xc = min(max(xs[c4], 0), WF - 1);
                const int yc = min(max(ys[c4], 0), HF - 1);
                offc[c4] = yc * WF + xc;
                wv[c4]   = v ? wc[c4] : 0.0f;
            }
            const float wn = wss[n];
            const float* fbp = feats + (size_t)(b * NCAM + n) * CF * HWF;
            #pragma unroll
            for (int k = 0; k < 4; ++k) {
                const float* fc = fbp + (size_t)(lane + 64 * k) * HWF;
                const float sv = wv[0]*fc[offc[0]] + wv[1]*fc[offc[1]]
                               + wv[2]*fc[offc[2]] + wv[3]*fc[offc[3]];
                acc[k] += wn * sv;
            }
        }
        #pragma unroll
        for (int k = 0; k < 4; ++k)
            fa[wave][lane + 64 * k] = acc[k];
    }
    float racc[4] = {0.f,0.f,0.f,0.f};
    const int h0 = 4 * lane;
    for (int c0 = 0; c0 < HID; c0 += CHUNK) {
        __syncthreads();
        for (int i = tid; i < CHUNK * HID; i += 512)
            wolds[i >> 8][i & 255] = Wo[(size_t)(c0 + (i >> 8)) * HID + (i & 255)];
        __syncthreads();
        #pragma unroll 8
        for (int c = 0; c < CHUNK; ++c) {
            const float fav = fa[wave][c0 + c];
            const float4 wv4 = *reinterpret_cast<const float4*>(&wolds[c][h0]);
            racc[0] += fav * wv4.x;
            racc[1] += fav * wv4.y;
            racc[2] += fav * wv4.z;
            racc[3] += fav * wv4.w;
        }
    }
    float4 o;
    o.x = racc[0] + bo[h0 + 0] + query[qrow + h0 + 0];
    o.y = racc[1] + bo[h0 + 1] + query[qrow + h0 + 1];
    o.z = racc[2] + bo[h0 + 2] + query[qrow + h0 + 2];
    o.w = racc[3] + bo[h0 + 3] + query[qrow + h0 + 3];
    *reinterpret_cast<float4*>(&out[qrow + h0]) = o;
}

extern "C" void kernel_launch(void* const* d_in, const int* in_sizes, int n_in,
                              void* d_out, int out_size, void* d_ws, size_t ws_size,
                              hipStream_t stream) {
    const float* query     = (const float*)d_in[0];
    const float* query_pos = (const float*)d_in[1];
    const float* rho       = (const float*)d_in[2];
    const float* phi       = (const float*)d_in[3];
    const float* zz        = (const float*)d_in[4];
    const float* feats     = (const float*)d_in[5];
    const float* l2i       = (const float*)d_in[6];
    const float* intervals = (const float*)d_in[7];
    const float* pc_range  = (const float*)d_in[8];
    const float* img_size  = (const float*)d_in[9];
    const float* Wa        = (const float*)d_in[10];
    const float* ba        = (const float*)d_in[11];
    const float* Wo        = (const float*)d_in[12];
    const float* bo        = (const float*)d_in[13];
    float* out = (float*)d_out;

    const size_t featsT_bytes = (size_t)NIMG * HWF * CF * 2;   // 8,601,600
    const size_t woT_bytes    = (size_t)HID * HID * 2;         // 131,072
    const size_t waT_bytes    = (size_t)32 * HID * 2;          // 16,384
    const size_t ws_bytes     = (size_t)BS * NQ * 8 * 4;       // 1,048,576
    const size_t gxy_bytes    = (size_t)BS * NQ * 12 * 4;      // 1,572,864
    const size_t need_small   = featsT_bytes + woT_bytes + waT_bytes;
    const size_t need_full    = featsT_bytes + woT_bytes + ws_bytes + gxy_bytes;

    if (ws_size >= need_full) {
        unsigned short* featsT = (unsigned short*)d_ws;
        unsigned short* WoT    = (unsigned short*)((char*)d_ws + featsT_bytes);
        float*          wsb    = (float*)((char*)d_ws + featsT_bytes + woT_bytes);
        float*          gxy    = (float*)((char*)d_ws + featsT_bytes + woT_bytes + ws_bytes);
        prep_aw<<<1872, 256, 0, stream>>>(feats, Wo, Wa, query, query_pos, ba,
                                          rho, phi, zz, l2i, intervals, pc_range,
                                          img_size, featsT, WoT, wsb, gxy, out);
        ca_main14<<<2048, 512, 0, stream>>>(query, featsT, wsb, gxy, WoT, bo, out);
    } else if (ws_size >= need_small) {
        unsigned short* featsT = (unsigned short*)d_ws;
        unsigned short* WoT    = (unsigned short*)((char*)d_ws + featsT_bytes);
        unsigned short* WaT    = (unsigned short*)((char*)d_ws + featsT_bytes + woT_bytes);
        prep_all<<<600, 256, 0, stream>>>(feats, Wo, Wa, featsT, WoT, WaT);
        ca_fused3<<<2048, 512, 0, stream>>>(query, query_pos, rho, phi, zz,
                                            featsT, l2i, intervals, pc_range,
                                            img_size, WaT, ba, WoT, bo, out);
    } else {
        ca_fused_fb<<<(BS * NQ) / 8, 512, 0, stream>>>(query, query_pos, rho, phi, zz,
                                                       feats, l2i, intervals, pc_range,
                                                       img_size, Wa, ba, Wo, bo, out);
    }
}